// Round 1
// baseline (731.573 us; speedup 1.0000x reference)
//
#include <hip/hip_runtime.h>
#include <cstddef>
#include <cstdint>

// ---------------- types / helpers ----------------
typedef short s16x8 __attribute__((ext_vector_type(8)));
typedef unsigned short u16x4 __attribute__((ext_vector_type(4)));
typedef unsigned short u16x8 __attribute__((ext_vector_type(8)));
typedef float f32x4 __attribute__((ext_vector_type(4)));

__device__ __forceinline__ unsigned short f2bf(float f) {
  unsigned int u = __float_as_uint(f);
  u = (u + 0x7fffu + ((u >> 16) & 1u)) >> 16;
  return (unsigned short)u;
}
__device__ __forceinline__ float bf2f(unsigned short u) {
  return __uint_as_float(((unsigned int)u) << 16);
}

__device__ __forceinline__ void gl2lds16(const unsigned short* g, unsigned short* l) {
  __builtin_amdgcn_global_load_lds(
      (const __attribute__((address_space(1))) unsigned int*)g,
      (__attribute__((address_space(3))) unsigned int*)l, 16, 0, 0);
}

static inline size_t alignup(size_t x) { return (x + 255) & ~(size_t)255; }

// ---------------- graph preprocessing ----------------
__global__ void count_kernel(const int* __restrict__ dst, int* __restrict__ counts, int E) {
  int e = blockIdx.x * blockDim.x + threadIdx.x;
  if (e < E) atomicAdd(&counts[dst[e]], 1);
}

__global__ void invsqrt_kernel(const int* __restrict__ counts, float* __restrict__ inv_s, int n) {
  int i = blockIdx.x * blockDim.x + threadIdx.x;
  if (i < n) inv_s[i] = rsqrtf((float)(counts[i] + 1));  // +1 self loop
}

__global__ void block_sum_kernel(const int* __restrict__ counts, int* __restrict__ bsum, int n) {
  __shared__ int red[256];
  int i = blockIdx.x * 256 + threadIdx.x;
  red[threadIdx.x] = (i < n) ? counts[i] : 0;
  __syncthreads();
  #pragma unroll
  for (int o = 128; o > 0; o >>= 1) {
    if (threadIdx.x < o) red[threadIdx.x] += red[threadIdx.x + o];
    __syncthreads();
  }
  if (threadIdx.x == 0) bsum[blockIdx.x] = red[0];
}

__global__ void scan_bsum_kernel(int* __restrict__ bsum, int nb) {
  __shared__ int s[256];
  int t = threadIdx.x;
  s[t] = (t < nb) ? bsum[t] : 0;
  __syncthreads();
  #pragma unroll
  for (int o = 1; o < 256; o <<= 1) {
    int v = (t >= o) ? s[t - o] : 0;
    __syncthreads();
    s[t] += v;
    __syncthreads();
  }
  if (t < nb) bsum[t] = (t == 0) ? 0 : s[t - 1];  // exclusive
}

__global__ void scan_apply_kernel(const int* __restrict__ counts, const int* __restrict__ bpre,
                                  int* __restrict__ offsets, int n) {
  __shared__ int s[256];
  int t = threadIdx.x;
  int i = blockIdx.x * 256 + t;
  s[t] = (i < n) ? counts[i] : 0;
  __syncthreads();
  #pragma unroll
  for (int o = 1; o < 256; o <<= 1) {
    int v = (t >= o) ? s[t - o] : 0;
    __syncthreads();
    s[t] += v;
    __syncthreads();
  }
  if (i < n) offsets[i + 1] = s[t] + bpre[blockIdx.x];
  if (i == 0) offsets[0] = 0;
}

__global__ void fill_kernel(const int* __restrict__ src, const int* __restrict__ dst,
                            const int* __restrict__ offsets, int* __restrict__ cursor,
                            int* __restrict__ csr_src, int E) {
  int e = blockIdx.x * blockDim.x + threadIdx.x;
  if (e >= E) return;
  int d = dst[e];
  int pos = atomicAdd(&cursor[d], 1);
  csr_src[offsets[d] + pos] = src[e];
}

// ---------------- weight transpose + bf16:  W[K][N] f32 -> Wt[N][K] bf16 ----------------
__global__ void transpose_w_kernel(const float* __restrict__ W, unsigned short* __restrict__ Wt,
                                   int K, int N) {
  __shared__ float tile[32][33];
  int k0 = blockIdx.x * 32, n0 = blockIdx.y * 32;
  int tx = threadIdx.x & 31, ty = threadIdx.x >> 5;
  #pragma unroll
  for (int i = 0; i < 32; i += 8)
    tile[ty + i][tx] = W[(size_t)(k0 + ty + i) * N + n0 + tx];
  __syncthreads();
  #pragma unroll
  for (int i = 0; i < 32; i += 8)
    Wt[(size_t)(n0 + ty + i) * K + k0 + tx] = f2bf(tile[tx][ty + i]);
}

// ---------------- GEMM1: f32 A[M][1536] (cvt->bf16 in staging) x Bt[512][1536] -> C[M][512] bf16
// 128x128 tile, BK=64, 4 waves. A: reg-staged global->cvt_pk->ds_write (dest-side XOR swizzle).
// B: global_load_lds(16B) with pre-swizzled source column (same involution).
// Bijective XCD-aware tile remap (m204).
__global__ __launch_bounds__(256) void gemm1_kernel(
    const float* __restrict__ A, const unsigned short* __restrict__ B,
    unsigned short* __restrict__ C, int M) {
  __shared__ __align__(16) unsigned short As[128 * 64];
  __shared__ __align__(16) unsigned short Bs[128 * 64];
  const int K = 1536;
  int tid = threadIdx.x, lane = tid & 63, w = tid >> 6;

  // bijective XCD swizzle: consecutive remapped ids stay on one XCD
  int nwg = gridDim.x * gridDim.y;
  int orig = blockIdx.y * gridDim.x + blockIdx.x;
  int q = nwg >> 3, r = nwg & 7;
  int xcd = orig & 7, loc = orig >> 3;
  int wg = (xcd < r) ? xcd * (q + 1) + loc : r * (q + 1) + (xcd - r) * q + loc;
  int bx = wg & 3, by = wg >> 2;  // gridDim.x == 4

  int m0 = by * 128, n0 = bx * 128;
  int wm = (w >> 1) * 64, wn = (w & 1) * 64;

  f32x4 acc[4][4];
  #pragma unroll
  for (int i = 0; i < 4; i++)
    #pragma unroll
    for (int j = 0; j < 4; j++) acc[i][j] = (f32x4){0.f, 0.f, 0.f, 0.f};

  int srow[4], sgc[4], adst[4];
  const float* aptr[4];
  bool aok[4];
  #pragma unroll
  for (int i = 0; i < 4; i++) {
    int s = i * 256 + tid;
    int row = s >> 3, j = s & 7;
    srow[i] = row;
    sgc[i] = (j ^ (row & 7)) << 3;            // swizzled column (elements)
    adst[i] = row * 64 + sgc[i];              // As dest element offset (16B aligned)
    aok[i] = (m0 + row) < M;
    aptr[i] = A + (size_t)(m0 + row) * K + j * 8;  // linear source column
  }

  for (int k0 = 0; k0 < K; k0 += 64) {
    #pragma unroll
    for (int i = 0; i < 4; i++) {
      // ---- A: load 8 f32, hw-convert to bf16, ds_write to swizzled dest ----
      f32x4 a0 = (f32x4){0.f, 0.f, 0.f, 0.f}, a1 = (f32x4){0.f, 0.f, 0.f, 0.f};
      if (aok[i]) {
        const f32x4* p = reinterpret_cast<const f32x4*>(aptr[i] + k0);
        a0 = p[0];
        a1 = p[1];
      }
      unsigned int r0, r1, r2, r3;
      asm("v_cvt_pk_bf16_f32 %0, %1, %2" : "=v"(r0) : "v"(a0[0]), "v"(a0[1]));
      asm("v_cvt_pk_bf16_f32 %0, %1, %2" : "=v"(r1) : "v"(a0[2]), "v"(a0[3]));
      asm("v_cvt_pk_bf16_f32 %0, %1, %2" : "=v"(r2) : "v"(a1[0]), "v"(a1[1]));
      asm("v_cvt_pk_bf16_f32 %0, %1, %2" : "=v"(r3) : "v"(a1[2]), "v"(a1[3]));
      uint4 pk;
      pk.x = r0; pk.y = r1; pk.z = r2; pk.w = r3;
      *reinterpret_cast<uint4*>(&As[adst[i]]) = pk;
      // ---- B: direct-to-LDS with pre-swizzled source ----
      int s = i * 256 + tid;
      gl2lds16(&B[(size_t)(n0 + srow[i]) * K + k0 + sgc[i]], &Bs[s * 8]);
    }
    __syncthreads();
    #pragma unroll
    for (int ks = 0; ks < 2; ks++) {
      s16x8 af[4], bfr[4];
      int jc = ks * 4 + (lane >> 4);
      #pragma unroll
      for (int i = 0; i < 4; i++) {
        int rr = wm + i * 16 + (lane & 15);
        af[i] = *reinterpret_cast<const s16x8*>(&As[rr * 64 + ((jc ^ (rr & 7)) << 3)]);
        int rn = wn + i * 16 + (lane & 15);
        bfr[i] = *reinterpret_cast<const s16x8*>(&Bs[rn * 64 + ((jc ^ (rn & 7)) << 3)]);
      }
      #pragma unroll
      for (int i = 0; i < 4; i++)
        #pragma unroll
        for (int j = 0; j < 4; j++)
          acc[i][j] = __builtin_amdgcn_mfma_f32_16x16x32_bf16(af[i], bfr[j], acc[i][j], 0, 0, 0);
    }
    __syncthreads();
  }
  #pragma unroll
  for (int i = 0; i < 4; i++) {
    #pragma unroll
    for (int j = 0; j < 4; j++) {
      int col = n0 + wn + j * 16 + (lane & 15);
      #pragma unroll
      for (int r2 = 0; r2 < 4; r2++) {
        int row = m0 + wm + i * 16 + (lane >> 4) * 4 + r2;
        if (row < M) C[(size_t)row * 512 + col] = f2bf(acc[i][j][r2]);
      }
    }
  }
}

// ---------------- GEMM2: bf16 A (BN1+ReLU fused on load) x W2t bf16 -> C bf16 ----------------
#define LDT 72
__global__ __launch_bounds__(256) void gemm2_kernel(
    const unsigned short* __restrict__ A, const unsigned short* __restrict__ Bt,
    const float* __restrict__ sc, const float* __restrict__ sh,
    unsigned short* __restrict__ C, int M) {
  const int N = 128, K = 512;
  __shared__ unsigned short As[128 * LDT];
  __shared__ unsigned short Bs[128 * LDT];
  int tid = threadIdx.x;
  int m0 = blockIdx.y * 128;
  int w = tid >> 6, lane = tid & 63;
  int wm = (w >> 1) * 64, wn = (w & 1) * 64;

  f32x4 acc[4][4];
  #pragma unroll
  for (int i = 0; i < 4; i++)
    #pragma unroll
    for (int j = 0; j < 4; j++) acc[i][j] = (f32x4){0.f, 0.f, 0.f, 0.f};

  for (int k0 = 0; k0 < K; k0 += 64) {
    // stage A: BN+ReLU on the fly
    #pragma unroll
    for (int r = 0; r < 4; r++) {
      int idx = r * 256 + tid;        // 0..1023
      int row = idx >> 3;             // 0..127
      int seg = (idx & 7) * 8;        // 0..56
      int gr = m0 + row;
      u16x8 v = (u16x8){0, 0, 0, 0, 0, 0, 0, 0};
      if (gr < M) v = *reinterpret_cast<const u16x8*>(&A[(size_t)gr * K + k0 + seg]);
      int c = k0 + seg;
      u16x8 p;
      #pragma unroll
      for (int j = 0; j < 8; j++) {
        float f = fmaxf(bf2f(v[j]) * sc[c + j] + sh[c + j], 0.f);
        p[j] = f2bf(f);
      }
      *reinterpret_cast<u16x8*>(&As[row * LDT + seg]) = p;
    }
    // stage B
    #pragma unroll
    for (int r = 0; r < 4; r++) {
      int idx = r * 256 + tid;
      int n = idx >> 3;
      int seg = (idx & 7) * 8;
      u16x8 v = *reinterpret_cast<const u16x8*>(&Bt[(size_t)n * K + k0 + seg]);
      *reinterpret_cast<u16x8*>(&Bs[n * LDT + seg]) = v;
    }
    __syncthreads();
    #pragma unroll
    for (int ks = 0; ks < 2; ks++) {
      s16x8 af[4], bfr[4];
      #pragma unroll
      for (int i = 0; i < 4; i++) {
        af[i]  = *reinterpret_cast<const s16x8*>(&As[(wm + i * 16 + (lane & 15)) * LDT + ks * 32 + (lane >> 4) * 8]);
        bfr[i] = *reinterpret_cast<const s16x8*>(&Bs[(wn + i * 16 + (lane & 15)) * LDT + ks * 32 + (lane >> 4) * 8]);
      }
      #pragma unroll
      for (int i = 0; i < 4; i++)
        #pragma unroll
        for (int j = 0; j < 4; j++)
          acc[i][j] = __builtin_amdgcn_mfma_f32_16x16x32_bf16(af[i], bfr[j], acc[i][j], 0, 0, 0);
    }
    __syncthreads();
  }
  #pragma unroll
  for (int i = 0; i < 4; i++) {
    #pragma unroll
    for (int j = 0; j < 4; j++) {
      int col = wn + j * 16 + (lane & 15);
      #pragma unroll
      for (int r = 0; r < 4; r++) {
        int row = m0 + wm + i * 16 + (lane >> 4) * 4 + r;
        if (row < M) C[(size_t)row * N + col] = f2bf(acc[i][j][r]);
      }
    }
  }
}

// ---------------- aggregation (bf16 in / bf16 out, fp32 accum), wave per node ----------------
// bias dropped: BatchNorm is invariant to per-channel constant shift.
__global__ void agg512_kernel(const unsigned short* __restrict__ h, const int* __restrict__ offsets,
                              const int* __restrict__ csr, const float* __restrict__ inv_s,
                              unsigned short* __restrict__ out, int n) {
  int wv = threadIdx.x >> 6, lane = threadIdx.x & 63;
  int node = blockIdx.x * 4 + wv;
  if (node >= n) return;
  const u16x8* h8 = reinterpret_cast<const u16x8*>(h);  // 64 segs/row
  float di = inv_s[node];
  size_t rb = (size_t)node * 64;
  float acc[8];
  u16x8 v0 = h8[rb + lane];
  float dd = di * di;
  #pragma unroll
  for (int j = 0; j < 8; j++) acc[j] = bf2f(v0[j]) * dd;
  int e = offsets[node], e1 = offsets[node + 1];
  for (; e + 1 < e1; e += 2) {
    int sA = csr[e], sB = csr[e + 1];
    float wA = inv_s[sA] * di, wB = inv_s[sB] * di;
    u16x8 vA = h8[(size_t)sA * 64 + lane];
    u16x8 vB = h8[(size_t)sB * 64 + lane];
    #pragma unroll
    for (int j = 0; j < 8; j++) acc[j] += bf2f(vA[j]) * wA + bf2f(vB[j]) * wB;
  }
  if (e < e1) {
    int sA = csr[e];
    float wA = inv_s[sA] * di;
    u16x8 vA = h8[(size_t)sA * 64 + lane];
    #pragma unroll
    for (int j = 0; j < 8; j++) acc[j] += bf2f(vA[j]) * wA;
  }
  u16x8 o;
  #pragma unroll
  for (int j = 0; j < 8; j++) o[j] = f2bf(acc[j]);
  reinterpret_cast<u16x8*>(out)[rb + lane] = o;
}

__global__ void agg128_kernel(const unsigned short* __restrict__ h, const int* __restrict__ offsets,
                              const int* __restrict__ csr, const float* __restrict__ inv_s,
                              unsigned short* __restrict__ out, int n) {
  int wv = threadIdx.x >> 6, lane = threadIdx.x & 63;
  int node = blockIdx.x * 4 + wv;
  if (node >= n) return;
  const unsigned int* h2 = reinterpret_cast<const unsigned int*>(h);  // 64 uints/row
  float di = inv_s[node];
  size_t rb = (size_t)node * 64;
  unsigned int u0 = h2[rb + lane];
  float dd = di * di;
  float alo = __uint_as_float(u0 << 16) * dd;
  float ahi = __uint_as_float(u0 & 0xffff0000u) * dd;
  int e = offsets[node], e1 = offsets[node + 1];
  for (; e + 1 < e1; e += 2) {
    int sA = csr[e], sB = csr[e + 1];
    float wA = inv_s[sA] * di, wB = inv_s[sB] * di;
    unsigned int uA = h2[(size_t)sA * 64 + lane];
    unsigned int uB = h2[(size_t)sB * 64 + lane];
    alo += __uint_as_float(uA << 16) * wA + __uint_as_float(uB << 16) * wB;
    ahi += __uint_as_float(uA & 0xffff0000u) * wA + __uint_as_float(uB & 0xffff0000u) * wB;
  }
  if (e < e1) {
    int sA = csr[e];
    float wA = inv_s[sA] * di;
    unsigned int uA = h2[(size_t)sA * 64 + lane];
    alo += __uint_as_float(uA << 16) * wA;
    ahi += __uint_as_float(uA & 0xffff0000u) * wA;
  }
  unsigned int uo = ((unsigned int)f2bf(ahi) << 16) | (unsigned int)f2bf(alo);
  reinterpret_cast<unsigned int*>(out)[rb + lane] = uo;
}

// ---------------- batch-norm stats (bf16 input) / finalize ----------------
__global__ void bn_stats512_kernel(const unsigned short* __restrict__ x, float* __restrict__ accum,
                                   int nrows, int rpb) {
  int r0 = blockIdx.x * rpb, r1 = min(nrows, r0 + rpb);
  int t = threadIdx.x;  // 256; channels 2t, 2t+1
  const unsigned int* x2 = reinterpret_cast<const unsigned int*>(x);
  float s0 = 0.f, q0 = 0.f, s1 = 0.f, q1 = 0.f;
  for (int r = r0; r < r1; r++) {
    unsigned int u = x2[(size_t)r * 256 + t];
    float lo = __uint_as_float(u << 16);
    float hi = __uint_as_float(u & 0xffff0000u);
    s0 += lo; q0 += lo * lo; s1 += hi; q1 += hi * hi;
  }
  atomicAdd(&accum[2 * t], s0);
  atomicAdd(&accum[2 * t + 1], s1);
  atomicAdd(&accum[512 + 2 * t], q0);
  atomicAdd(&accum[512 + 2 * t + 1], q1);
}

__global__ void bn_stats128_kernel(const unsigned short* __restrict__ x, float* __restrict__ accum,
                                   int nrows, int rpb) {
  int r0 = blockIdx.x * rpb, r1 = min(nrows, r0 + rpb);
  int t = threadIdx.x;
  int colu = t & 63, rofs = t >> 6;  // 4 rows in flight
  const unsigned int* x2 = reinterpret_cast<const unsigned int*>(x);
  float s0 = 0.f, q0 = 0.f, s1 = 0.f, q1 = 0.f;
  for (int r = r0 + rofs; r < r1; r += 4) {
    unsigned int u = x2[(size_t)r * 64 + colu];
    float lo = __uint_as_float(u << 16);
    float hi = __uint_as_float(u & 0xffff0000u);
    s0 += lo; q0 += lo * lo; s1 += hi; q1 += hi * hi;
  }
  atomicAdd(&accum[2 * colu], s0);
  atomicAdd(&accum[2 * colu + 1], s1);
  atomicAdd(&accum[128 + 2 * colu], q0);
  atomicAdd(&accum[128 + 2 * colu + 1], q1);
}

__global__ void bn_finalize_kernel(const float* __restrict__ accum, const float* __restrict__ gamma,
                                   const float* __restrict__ beta, float* __restrict__ scale,
                                   float* __restrict__ shift, int D, float invN) {
  int c = blockIdx.x * blockDim.x + threadIdx.x;
  if (c >= D) return;
  float mean = accum[c] * invN;
  float var = accum[D + c] * invN - mean * mean;
  float sc = gamma[c] * rsqrtf(var + 1e-5f);
  scale[c] = sc;
  shift[c] = beta[c] - mean * sc;
}

// ---------------- layer 3: tiny GEMM K=128, N=5 (fp32), BN2+ReLU fused, bf16 A ----------------
__global__ void gemm3_kernel(const unsigned short* __restrict__ A, const float* __restrict__ W,
                             const float* __restrict__ sc, const float* __restrict__ sh,
                             float* __restrict__ C, int M) {
  __shared__ float Ws[128 * 5];
  __shared__ float scs[128], shs[128];
  int tid = threadIdx.x;
  for (int i = tid; i < 128 * 5; i += blockDim.x) Ws[i] = W[i];
  if (tid < 128) { scs[tid] = sc[tid]; shs[tid] = sh[tid]; }
  __syncthreads();
  int row = blockIdx.x * blockDim.x + tid;
  if (row >= M) return;
  float acc[5] = {0.f, 0.f, 0.f, 0.f, 0.f};
  const u16x8* a8 = reinterpret_cast<const u16x8*>(A + (size_t)row * 128);
  for (int k8 = 0; k8 < 16; k8++) {
    u16x8 v = a8[k8];
    int k = k8 * 8;
    #pragma unroll
    for (int j = 0; j < 8; j++) {
      float f = fmaxf(bf2f(v[j]) * scs[k + j] + shs[k + j], 0.f);
      #pragma unroll
      for (int c = 0; c < 5; c++) acc[c] += f * Ws[(k + j) * 5 + c];
    }
  }
  #pragma unroll
  for (int j = 0; j < 5; j++) C[(size_t)row * 5 + j] = acc[j];
}

// ---------------- final aggregation + b3 + log_softmax ----------------
__global__ void agg3_lsm_kernel(const float* __restrict__ h, const int* __restrict__ offsets,
                                const int* __restrict__ csr, const float* __restrict__ inv_s,
                                const float* __restrict__ b3, float* __restrict__ out, int n) {
  int node = blockIdx.x * blockDim.x + threadIdx.x;
  if (node >= n) return;
  float di = inv_s[node];
  float acc[5];
  #pragma unroll
  for (int j = 0; j < 5; j++) acc[j] = h[(size_t)node * 5 + j] * di * di;
  int s0 = offsets[node], s1 = offsets[node + 1];
  for (int e = s0; e < s1; e++) {
    int s = csr[e];
    float wgt = inv_s[s] * di;
    #pragma unroll
    for (int j = 0; j < 5; j++) acc[j] += h[(size_t)s * 5 + j] * wgt;
  }
  #pragma unroll
  for (int j = 0; j < 5; j++) acc[j] += b3[j];
  float m = acc[0];
  #pragma unroll
  for (int j = 1; j < 5; j++) m = fmaxf(m, acc[j]);
  float sum = 0.f;
  #pragma unroll
  for (int j = 0; j < 5; j++) sum += expf(acc[j] - m);
  float lse = logf(sum);
  #pragma unroll
  for (int j = 0; j < 5; j++) out[(size_t)node * 5 + j] = acc[j] - m - lse;
}

// ---------------- launcher ----------------
extern "C" void kernel_launch(void* const* d_in, const int* in_sizes, int n_in,
                              void* d_out, int out_size, void* d_ws, size_t ws_size,
                              hipStream_t stream) {
  const float* x      = (const float*)d_in[0];
  const int*   ei     = (const int*)d_in[1];
  const float* W1     = (const float*)d_in[2];
  const float* b3     = (const float*)d_in[7];
  const float* W2     = (const float*)d_in[4];
  const float* W3     = (const float*)d_in[6];
  const float* gamma1 = (const float*)d_in[8];
  const float* beta1  = (const float*)d_in[9];
  const float* gamma2 = (const float*)d_in[10];
  const float* beta2  = (const float*)d_in[11];

  const int N = in_sizes[0] / 1536;
  const int E = in_sizes[1] / 2;
  const int* src = ei;
  const int* dst = ei + E;

  const int mblocks = (N + 127) / 128;      // 391
  const int nb = (N + 255) / 256;

  char* ws = (char*)d_ws;
  size_t szRA = alignup((size_t)N * 512 * sizeof(float));
  size_t szXB = alignup((size_t)(mblocks * 128) * 1536 * sizeof(unsigned short));
  char* RAb = ws;                            // region A (bf16 H1 / bf16 H2 / f32 H3)
  char* RBb = ws + szRA;                     // region B (was XB; now only G1/G2)
  char* sp = ws + szRA + szXB;
  int* counts   = (int*)sp;           sp += alignup((size_t)N * 4);
  int* cursor   = (int*)sp;           sp += alignup((size_t)N * 4);
  int* offsets  = (int*)sp;           sp += alignup((size_t)(N + 1) * 4);
  int* csr_src  = (int*)sp;           sp += alignup((size_t)E * 4);
  float* inv_s  = (float*)sp;         sp += alignup((size_t)N * 4);
  unsigned short* W1t = (unsigned short*)sp; sp += alignup((size_t)512 * 1536 * 2);
  unsigned short* W2t = (unsigned short*)sp; sp += alignup((size_t)128 * 512 * 2);
  float* accum  = (float*)sp;         sp += alignup(1024 * 4);
  float* sc1    = (float*)sp;         sp += alignup(512 * 4);
  float* sh1    = (float*)sp;         sp += alignup(512 * 4);
  float* sc2    = (float*)sp;         sp += alignup(128 * 4);
  float* sh2    = (float*)sp;         sp += alignup(128 * 4);
  int* bsum     = (int*)sp;           sp += alignup(256 * 4);

  unsigned short* H1  = (unsigned short*)RAb;  // N x 512 bf16
  unsigned short* G1  = (unsigned short*)RBb;  // N x 512 bf16 (post-agg)
  unsigned short* H2  = (unsigned short*)RAb;  // N x 128 bf16
  unsigned short* G2  = (unsigned short*)RBb;  // N x 128 bf16
  float*          H3  = (float*)RAb;           // N x 5 f32

  // ---- graph preprocessing ----
  hipMemsetAsync(counts, 0, (size_t)N * 4, stream);
  hipMemsetAsync(cursor, 0, (size_t)N * 4, stream);
  count_kernel<<<(E + 255) / 256, 256, 0, stream>>>(dst, counts, E);
  invsqrt_kernel<<<(N + 255) / 256, 256, 0, stream>>>(counts, inv_s, N);
  block_sum_kernel<<<nb, 256, 0, stream>>>(counts, bsum, N);
  scan_bsum_kernel<<<1, 256, 0, stream>>>(bsum, nb);
  scan_apply_kernel<<<nb, 256, 0, stream>>>(counts, bsum, offsets, N);
  fill_kernel<<<(E + 255) / 256, 256, 0, stream>>>(src, dst, offsets, cursor, csr_src, E);

  // ---- weights ----
  transpose_w_kernel<<<dim3(1536 / 32, 512 / 32), 256, 0, stream>>>(W1, W1t, 1536, 512);
  transpose_w_kernel<<<dim3(512 / 32, 128 / 32), 256, 0, stream>>>(W2, W2t, 512, 128);

  int aggblocks = (N + 3) / 4;
  int rpb = (N + 511) / 512;

  // ---- layer 1 (x f32 -> bf16 fused into A staging) ----
  gemm1_kernel<<<dim3(4, mblocks), 256, 0, stream>>>(x, W1t, H1, N);
  agg512_kernel<<<aggblocks, 256, 0, stream>>>(H1, offsets, csr_src, inv_s, G1, N);
  hipMemsetAsync(accum, 0, 1024 * 4, stream);
  bn_stats512_kernel<<<512, 256, 0, stream>>>(G1, accum, N, rpb);
  bn_finalize_kernel<<<2, 256, 0, stream>>>(accum, gamma1, beta1, sc1, sh1, 512, 1.0f / N);

  // ---- layer 2 (BN1+ReLU fused into A staging) ----
  gemm2_kernel<<<dim3(1, mblocks), 256, 0, stream>>>(G1, W2t, sc1, sh1, H2, N);
  agg128_kernel<<<aggblocks, 256, 0, stream>>>(H2, offsets, csr_src, inv_s, G2, N);
  hipMemsetAsync(accum, 0, 1024 * 4, stream);
  bn_stats128_kernel<<<512, 256, 0, stream>>>(G2, accum, N, rpb);
  bn_finalize_kernel<<<1, 256, 0, stream>>>(accum, gamma2, beta2, sc2, sh2, 128, 1.0f / N);

  // ---- layer 3 (BN2+ReLU fused) ----
  gemm3_kernel<<<(N + 255) / 256, 256, 0, stream>>>(G2, W3, sc2, sh2, H3, N);
  agg3_lsm_kernel<<<(N + 255) / 256, 256, 0, stream>>>(H3, offsets, csr_src, inv_s, b3,
                                                       (float*)d_out, N);
}

// Round 2
// 674.164 us; speedup vs baseline: 1.0852x; 1.0852x over previous
//
#include <hip/hip_runtime.h>
#include <cstddef>
#include <cstdint>

// ---------------- types / helpers ----------------
typedef short s16x8 __attribute__((ext_vector_type(8)));
typedef unsigned short u16x4 __attribute__((ext_vector_type(4)));
typedef unsigned short u16x8 __attribute__((ext_vector_type(8)));
typedef float f32x4 __attribute__((ext_vector_type(4)));

__device__ __forceinline__ unsigned short f2bf(float f) {
  unsigned int u = __float_as_uint(f);
  u = (u + 0x7fffu + ((u >> 16) & 1u)) >> 16;
  return (unsigned short)u;
}
__device__ __forceinline__ float bf2f(unsigned short u) {
  return __uint_as_float(((unsigned int)u) << 16);
}

__device__ __forceinline__ void gl2lds16(const unsigned short* g, unsigned short* l) {
  __builtin_amdgcn_global_load_lds(
      (const __attribute__((address_space(1))) unsigned int*)g,
      (__attribute__((address_space(3))) unsigned int*)l, 16, 0, 0);
}

static inline size_t alignup(size_t x) { return (x + 255) & ~(size_t)255; }

// ---------------- graph preprocessing ----------------
__global__ void count_kernel(const int* __restrict__ dst, int* __restrict__ counts, int E) {
  int e = blockIdx.x * blockDim.x + threadIdx.x;
  if (e < E) atomicAdd(&counts[dst[e]], 1);
}

__global__ void invsqrt_kernel(const int* __restrict__ counts, float* __restrict__ inv_s, int n) {
  int i = blockIdx.x * blockDim.x + threadIdx.x;
  if (i < n) inv_s[i] = rsqrtf((float)(counts[i] + 1));  // +1 self loop
}

__global__ void block_sum_kernel(const int* __restrict__ counts, int* __restrict__ bsum, int n) {
  __shared__ int red[256];
  int i = blockIdx.x * 256 + threadIdx.x;
  red[threadIdx.x] = (i < n) ? counts[i] : 0;
  __syncthreads();
  #pragma unroll
  for (int o = 128; o > 0; o >>= 1) {
    if (threadIdx.x < o) red[threadIdx.x] += red[threadIdx.x + o];
    __syncthreads();
  }
  if (threadIdx.x == 0) bsum[blockIdx.x] = red[0];
}

__global__ void scan_bsum_kernel(int* __restrict__ bsum, int nb) {
  __shared__ int s[256];
  int t = threadIdx.x;
  s[t] = (t < nb) ? bsum[t] : 0;
  __syncthreads();
  #pragma unroll
  for (int o = 1; o < 256; o <<= 1) {
    int v = (t >= o) ? s[t - o] : 0;
    __syncthreads();
    s[t] += v;
    __syncthreads();
  }
  if (t < nb) bsum[t] = (t == 0) ? 0 : s[t - 1];  // exclusive
}

__global__ void scan_apply_kernel(const int* __restrict__ counts, const int* __restrict__ bpre,
                                  int* __restrict__ offsets, int n) {
  __shared__ int s[256];
  int t = threadIdx.x;
  int i = blockIdx.x * 256 + t;
  s[t] = (i < n) ? counts[i] : 0;
  __syncthreads();
  #pragma unroll
  for (int o = 1; o < 256; o <<= 1) {
    int v = (t >= o) ? s[t - o] : 0;
    __syncthreads();
    s[t] += v;
    __syncthreads();
  }
  if (i < n) offsets[i + 1] = s[t] + bpre[blockIdx.x];
  if (i == 0) offsets[0] = 0;
}

__global__ void fill_kernel(const int* __restrict__ src, const int* __restrict__ dst,
                            const int* __restrict__ offsets, int* __restrict__ cursor,
                            int* __restrict__ csr_src, int E) {
  int e = blockIdx.x * blockDim.x + threadIdx.x;
  if (e >= E) return;
  int d = dst[e];
  int pos = atomicAdd(&cursor[d], 1);
  csr_src[offsets[d] + pos] = src[e];
}

// ---------------- weight transpose + bf16:  W[K][N] f32 -> Wt[N][K] bf16 ----------------
__global__ void transpose_w_kernel(const float* __restrict__ W, unsigned short* __restrict__ Wt,
                                   int K, int N) {
  __shared__ float tile[32][33];
  int k0 = blockIdx.x * 32, n0 = blockIdx.y * 32;
  int tx = threadIdx.x & 31, ty = threadIdx.x >> 5;
  #pragma unroll
  for (int i = 0; i < 32; i += 8)
    tile[ty + i][tx] = W[(size_t)(k0 + ty + i) * N + n0 + tx];
  __syncthreads();
  #pragma unroll
  for (int i = 0; i < 32; i += 8)
    Wt[(size_t)(n0 + ty + i) * K + k0 + tx] = f2bf(tile[tx][ty + i]);
}

// ---------------- GEMM1: f32 A[M][1536] (cvt->bf16 in staging) x Bt[512][1536] -> C[M][512] bf16
// 2-phase double-buffered pipeline (T3 minimum recipe + T14 issue-early/write-late):
//   iter t: issue B gl2lds(t+1)->buf^1, issue A f32 reg-loads(t+1)   [fly under MFMA]
//           MFMA on buf[cur]
//           cvt+ds_write A(t+1)->buf^1                               [loads already landed]
//           one __syncthreads per tile
// Dest-side XOR swizzle on A (reg-staged), pre-swizzled source on B (gl2lds). m204 XCD remap.
__global__ __launch_bounds__(256) void gemm1_kernel(
    const float* __restrict__ A, const unsigned short* __restrict__ B,
    unsigned short* __restrict__ C, int M) {
  __shared__ __align__(16) unsigned short As[2][128 * 64];
  __shared__ __align__(16) unsigned short Bs[2][128 * 64];
  const int K = 1536;
  const int NT = K / 64;  // 24
  int tid = threadIdx.x, lane = tid & 63, w = tid >> 6;

  // bijective XCD swizzle: consecutive remapped ids stay on one XCD
  int nwg = gridDim.x * gridDim.y;
  int orig = blockIdx.y * gridDim.x + blockIdx.x;
  int q = nwg >> 3, r = nwg & 7;
  int xcd = orig & 7, loc = orig >> 3;
  int wg = (xcd < r) ? xcd * (q + 1) + loc : r * (q + 1) + (xcd - r) * q + loc;
  int bx = wg & 3, by = wg >> 2;  // gridDim.x == 4

  int m0 = by * 128, n0 = bx * 128;
  int wm = (w >> 1) * 64, wn = (w & 1) * 64;

  f32x4 acc[4][4];
  #pragma unroll
  for (int i = 0; i < 4; i++)
    #pragma unroll
    for (int j = 0; j < 4; j++) acc[i][j] = (f32x4){0.f, 0.f, 0.f, 0.f};

  int srow[4], sgc[4], adst[4];
  const float* aptr[4];
  bool aok[4];
  #pragma unroll
  for (int i = 0; i < 4; i++) {
    int s = i * 256 + tid;
    int row = s >> 3, j = s & 7;
    srow[i] = row;
    sgc[i] = (j ^ (row & 7)) << 3;            // swizzled column (elements)
    adst[i] = row * 64 + sgc[i];              // As dest element offset (16B aligned)
    aok[i] = (m0 + row) < M;
    aptr[i] = A + (size_t)(m0 + row) * K + j * 8;  // linear source column
  }

  // ---- prologue: stage tile 0 into buf 0 ----
  #pragma unroll
  for (int i = 0; i < 4; i++) {
    int s = i * 256 + tid;
    gl2lds16(&B[(size_t)(n0 + srow[i]) * K + sgc[i]], &Bs[0][s * 8]);
    f32x4 a0 = (f32x4){0.f, 0.f, 0.f, 0.f}, a1 = (f32x4){0.f, 0.f, 0.f, 0.f};
    if (aok[i]) {
      const f32x4* p = reinterpret_cast<const f32x4*>(aptr[i]);
      a0 = p[0];
      a1 = p[1];
    }
    unsigned int r0, r1, r2, r3;
    asm("v_cvt_pk_bf16_f32 %0, %1, %2" : "=v"(r0) : "v"(a0[0]), "v"(a0[1]));
    asm("v_cvt_pk_bf16_f32 %0, %1, %2" : "=v"(r1) : "v"(a0[2]), "v"(a0[3]));
    asm("v_cvt_pk_bf16_f32 %0, %1, %2" : "=v"(r2) : "v"(a1[0]), "v"(a1[1]));
    asm("v_cvt_pk_bf16_f32 %0, %1, %2" : "=v"(r3) : "v"(a1[2]), "v"(a1[3]));
    uint4 pk;
    pk.x = r0; pk.y = r1; pk.z = r2; pk.w = r3;
    *reinterpret_cast<uint4*>(&As[0][adst[i]]) = pk;
  }
  __syncthreads();

  int cur = 0;
  for (int t = 0; t < NT; t++) {
    int k1 = (t + 1) * 64;
    f32x4 na0[4], na1[4];
    bool pf = (t + 1) < NT;
    if (pf) {
      // issue next tile's loads BEFORE the MFMA phase (latency hides under compute)
      #pragma unroll
      for (int i = 0; i < 4; i++) {
        int s = i * 256 + tid;
        gl2lds16(&B[(size_t)(n0 + srow[i]) * K + k1 + sgc[i]], &Bs[cur ^ 1][s * 8]);
        na0[i] = (f32x4){0.f, 0.f, 0.f, 0.f};
        na1[i] = (f32x4){0.f, 0.f, 0.f, 0.f};
        if (aok[i]) {
          const f32x4* p = reinterpret_cast<const f32x4*>(aptr[i] + k1);
          na0[i] = p[0];
          na1[i] = p[1];
        }
      }
    }
    // ---- compute on buf[cur] ----
    #pragma unroll
    for (int ks = 0; ks < 2; ks++) {
      s16x8 af[4], bfr[4];
      int jc = ks * 4 + (lane >> 4);
      #pragma unroll
      for (int i = 0; i < 4; i++) {
        int rr = wm + i * 16 + (lane & 15);
        af[i] = *reinterpret_cast<const s16x8*>(&As[cur][rr * 64 + ((jc ^ (rr & 7)) << 3)]);
        int rn = wn + i * 16 + (lane & 15);
        bfr[i] = *reinterpret_cast<const s16x8*>(&Bs[cur][rn * 64 + ((jc ^ (rn & 7)) << 3)]);
      }
      #pragma unroll
      for (int i = 0; i < 4; i++)
        #pragma unroll
        for (int j = 0; j < 4; j++)
          acc[i][j] = __builtin_amdgcn_mfma_f32_16x16x32_bf16(af[i], bfr[j], acc[i][j], 0, 0, 0);
    }
    // ---- write-late: A(t+1) regs -> LDS buf^1 (loads have had the whole MFMA phase) ----
    if (pf) {
      #pragma unroll
      for (int i = 0; i < 4; i++) {
        unsigned int r0, r1, r2, r3;
        asm("v_cvt_pk_bf16_f32 %0, %1, %2" : "=v"(r0) : "v"(na0[i][0]), "v"(na0[i][1]));
        asm("v_cvt_pk_bf16_f32 %0, %1, %2" : "=v"(r1) : "v"(na0[i][2]), "v"(na0[i][3]));
        asm("v_cvt_pk_bf16_f32 %0, %1, %2" : "=v"(r2) : "v"(na1[i][0]), "v"(na1[i][1]));
        asm("v_cvt_pk_bf16_f32 %0, %1, %2" : "=v"(r3) : "v"(na1[i][2]), "v"(na1[i][3]));
        uint4 pk;
        pk.x = r0; pk.y = r1; pk.z = r2; pk.w = r3;
        *reinterpret_cast<uint4*>(&As[cur ^ 1][adst[i]]) = pk;
      }
    }
    __syncthreads();  // one barrier per tile: drains B DMA + A ds_writes; frees buf[cur]
    cur ^= 1;
  }

  #pragma unroll
  for (int i = 0; i < 4; i++) {
    #pragma unroll
    for (int j = 0; j < 4; j++) {
      int col = n0 + wn + j * 16 + (lane & 15);
      #pragma unroll
      for (int r2 = 0; r2 < 4; r2++) {
        int row = m0 + wm + i * 16 + (lane >> 4) * 4 + r2;
        if (row < M) C[(size_t)row * 512 + col] = f2bf(acc[i][j][r2]);
      }
    }
  }
}

// ---------------- GEMM2: bf16 A (BN1+ReLU fused on load) x W2t bf16 -> C bf16 ----------------
#define LDT 72
__global__ __launch_bounds__(256) void gemm2_kernel(
    const unsigned short* __restrict__ A, const unsigned short* __restrict__ Bt,
    const float* __restrict__ sc, const float* __restrict__ sh,
    unsigned short* __restrict__ C, int M) {
  const int N = 128, K = 512;
  __shared__ unsigned short As[128 * LDT];
  __shared__ unsigned short Bs[128 * LDT];
  int tid = threadIdx.x;
  int m0 = blockIdx.y * 128;
  int w = tid >> 6, lane = tid & 63;
  int wm = (w >> 1) * 64, wn = (w & 1) * 64;

  f32x4 acc[4][4];
  #pragma unroll
  for (int i = 0; i < 4; i++)
    #pragma unroll
    for (int j = 0; j < 4; j++) acc[i][j] = (f32x4){0.f, 0.f, 0.f, 0.f};

  for (int k0 = 0; k0 < K; k0 += 64) {
    // stage A: BN+ReLU on the fly
    #pragma unroll
    for (int r = 0; r < 4; r++) {
      int idx = r * 256 + tid;        // 0..1023
      int row = idx >> 3;             // 0..127
      int seg = (idx & 7) * 8;        // 0..56
      int gr = m0 + row;
      u16x8 v = (u16x8){0, 0, 0, 0, 0, 0, 0, 0};
      if (gr < M) v = *reinterpret_cast<const u16x8*>(&A[(size_t)gr * K + k0 + seg]);
      int c = k0 + seg;
      u16x8 p;
      #pragma unroll
      for (int j = 0; j < 8; j++) {
        float f = fmaxf(bf2f(v[j]) * sc[c + j] + sh[c + j], 0.f);
        p[j] = f2bf(f);
      }
      *reinterpret_cast<u16x8*>(&As[row * LDT + seg]) = p;
    }
    // stage B
    #pragma unroll
    for (int r = 0; r < 4; r++) {
      int idx = r * 256 + tid;
      int n = idx >> 3;
      int seg = (idx & 7) * 8;
      u16x8 v = *reinterpret_cast<const u16x8*>(&Bt[(size_t)n * K + k0 + seg]);
      *reinterpret_cast<u16x8*>(&Bs[n * LDT + seg]) = v;
    }
    __syncthreads();
    #pragma unroll
    for (int ks = 0; ks < 2; ks++) {
      s16x8 af[4], bfr[4];
      #pragma unroll
      for (int i = 0; i < 4; i++) {
        af[i]  = *reinterpret_cast<const s16x8*>(&As[(wm + i * 16 + (lane & 15)) * LDT + ks * 32 + (lane >> 4) * 8]);
        bfr[i] = *reinterpret_cast<const s16x8*>(&Bs[(wn + i * 16 + (lane & 15)) * LDT + ks * 32 + (lane >> 4) * 8]);
      }
      #pragma unroll
      for (int i = 0; i < 4; i++)
        #pragma unroll
        for (int j = 0; j < 4; j++)
          acc[i][j] = __builtin_amdgcn_mfma_f32_16x16x32_bf16(af[i], bfr[j], acc[i][j], 0, 0, 0);
    }
    __syncthreads();
  }
  #pragma unroll
  for (int i = 0; i < 4; i++) {
    #pragma unroll
    for (int j = 0; j < 4; j++) {
      int col = wn + j * 16 + (lane & 15);
      #pragma unroll
      for (int r = 0; r < 4; r++) {
        int row = m0 + wm + i * 16 + (lane >> 4) * 4 + r;
        if (row < M) C[(size_t)row * N + col] = f2bf(acc[i][j][r]);
      }
    }
  }
}

// ---------------- aggregation (bf16 in / bf16 out, fp32 accum), wave per node ----------------
// bias dropped: BatchNorm is invariant to per-channel constant shift.
__global__ void agg512_kernel(const unsigned short* __restrict__ h, const int* __restrict__ offsets,
                              const int* __restrict__ csr, const float* __restrict__ inv_s,
                              unsigned short* __restrict__ out, int n) {
  int wv = threadIdx.x >> 6, lane = threadIdx.x & 63;
  int node = blockIdx.x * 4 + wv;
  if (node >= n) return;
  const u16x8* h8 = reinterpret_cast<const u16x8*>(h);  // 64 segs/row
  float di = inv_s[node];
  size_t rb = (size_t)node * 64;
  float acc[8];
  u16x8 v0 = h8[rb + lane];
  float dd = di * di;
  #pragma unroll
  for (int j = 0; j < 8; j++) acc[j] = bf2f(v0[j]) * dd;
  int e = offsets[node], e1 = offsets[node + 1];
  for (; e + 1 < e1; e += 2) {
    int sA = csr[e], sB = csr[e + 1];
    float wA = inv_s[sA] * di, wB = inv_s[sB] * di;
    u16x8 vA = h8[(size_t)sA * 64 + lane];
    u16x8 vB = h8[(size_t)sB * 64 + lane];
    #pragma unroll
    for (int j = 0; j < 8; j++) acc[j] += bf2f(vA[j]) * wA + bf2f(vB[j]) * wB;
  }
  if (e < e1) {
    int sA = csr[e];
    float wA = inv_s[sA] * di;
    u16x8 vA = h8[(size_t)sA * 64 + lane];
    #pragma unroll
    for (int j = 0; j < 8; j++) acc[j] += bf2f(vA[j]) * wA;
  }
  u16x8 o;
  #pragma unroll
  for (int j = 0; j < 8; j++) o[j] = f2bf(acc[j]);
  reinterpret_cast<u16x8*>(out)[rb + lane] = o;
}

__global__ void agg128_kernel(const unsigned short* __restrict__ h, const int* __restrict__ offsets,
                              const int* __restrict__ csr, const float* __restrict__ inv_s,
                              unsigned short* __restrict__ out, int n) {
  int wv = threadIdx.x >> 6, lane = threadIdx.x & 63;
  int node = blockIdx.x * 4 + wv;
  if (node >= n) return;
  const unsigned int* h2 = reinterpret_cast<const unsigned int*>(h);  // 64 uints/row
  float di = inv_s[node];
  size_t rb = (size_t)node * 64;
  unsigned int u0 = h2[rb + lane];
  float dd = di * di;
  float alo = __uint_as_float(u0 << 16) * dd;
  float ahi = __uint_as_float(u0 & 0xffff0000u) * dd;
  int e = offsets[node], e1 = offsets[node + 1];
  for (; e + 1 < e1; e += 2) {
    int sA = csr[e], sB = csr[e + 1];
    float wA = inv_s[sA] * di, wB = inv_s[sB] * di;
    unsigned int uA = h2[(size_t)sA * 64 + lane];
    unsigned int uB = h2[(size_t)sB * 64 + lane];
    alo += __uint_as_float(uA << 16) * wA + __uint_as_float(uB << 16) * wB;
    ahi += __uint_as_float(uA & 0xffff0000u) * wA + __uint_as_float(uB & 0xffff0000u) * wB;
  }
  if (e < e1) {
    int sA = csr[e];
    float wA = inv_s[sA] * di;
    unsigned int uA = h2[(size_t)sA * 64 + lane];
    alo += __uint_as_float(uA << 16) * wA;
    ahi += __uint_as_float(uA & 0xffff0000u) * wA;
  }
  unsigned int uo = ((unsigned int)f2bf(ahi) << 16) | (unsigned int)f2bf(alo);
  reinterpret_cast<unsigned int*>(out)[rb + lane] = uo;
}

// ---------------- batch-norm stats (bf16 input) / finalize ----------------
__global__ void bn_stats512_kernel(const unsigned short* __restrict__ x, float* __restrict__ accum,
                                   int nrows, int rpb) {
  int r0 = blockIdx.x * rpb, r1 = min(nrows, r0 + rpb);
  int t = threadIdx.x;  // 256; channels 2t, 2t+1
  const unsigned int* x2 = reinterpret_cast<const unsigned int*>(x);
  float s0 = 0.f, q0 = 0.f, s1 = 0.f, q1 = 0.f;
  for (int r = r0; r < r1; r++) {
    unsigned int u = x2[(size_t)r * 256 + t];
    float lo = __uint_as_float(u << 16);
    float hi = __uint_as_float(u & 0xffff0000u);
    s0 += lo; q0 += lo * lo; s1 += hi; q1 += hi * hi;
  }
  atomicAdd(&accum[2 * t], s0);
  atomicAdd(&accum[2 * t + 1], s1);
  atomicAdd(&accum[512 + 2 * t], q0);
  atomicAdd(&accum[512 + 2 * t + 1], q1);
}

__global__ void bn_stats128_kernel(const unsigned short* __restrict__ x, float* __restrict__ accum,
                                   int nrows, int rpb) {
  int r0 = blockIdx.x * rpb, r1 = min(nrows, r0 + rpb);
  int t = threadIdx.x;
  int colu = t & 63, rofs = t >> 6;  // 4 rows in flight
  const unsigned int* x2 = reinterpret_cast<const unsigned int*>(x);
  float s0 = 0.f, q0 = 0.f, s1 = 0.f, q1 = 0.f;
  for (int r = r0 + rofs; r < r1; r += 4) {
    unsigned int u = x2[(size_t)r * 64 + colu];
    float lo = __uint_as_float(u << 16);
    float hi = __uint_as_float(u & 0xffff0000u);
    s0 += lo; q0 += lo * lo; s1 += hi; q1 += hi * hi;
  }
  atomicAdd(&accum[2 * colu], s0);
  atomicAdd(&accum[2 * colu + 1], s1);
  atomicAdd(&accum[128 + 2 * colu], q0);
  atomicAdd(&accum[128 + 2 * colu + 1], q1);
}

__global__ void bn_finalize_kernel(const float* __restrict__ accum, const float* __restrict__ gamma,
                                   const float* __restrict__ beta, float* __restrict__ scale,
                                   float* __restrict__ shift, int D, float invN) {
  int c = blockIdx.x * blockDim.x + threadIdx.x;
  if (c >= D) return;
  float mean = accum[c] * invN;
  float var = accum[D + c] * invN - mean * mean;
  float sc = gamma[c] * rsqrtf(var + 1e-5f);
  scale[c] = sc;
  shift[c] = beta[c] - mean * sc;
}

// ---------------- layer 3: tiny GEMM K=128, N=5 (fp32), BN2+ReLU fused, bf16 A ----------------
__global__ void gemm3_kernel(const unsigned short* __restrict__ A, const float* __restrict__ W,
                             const float* __restrict__ sc, const float* __restrict__ sh,
                             float* __restrict__ C, int M) {
  __shared__ float Ws[128 * 5];
  __shared__ float scs[128], shs[128];
  int tid = threadIdx.x;
  for (int i = tid; i < 128 * 5; i += blockDim.x) Ws[i] = W[i];
  if (tid < 128) { scs[tid] = sc[tid]; shs[tid] = sh[tid]; }
  __syncthreads();
  int row = blockIdx.x * blockDim.x + tid;
  if (row >= M) return;
  float acc[5] = {0.f, 0.f, 0.f, 0.f, 0.f};
  const u16x8* a8 = reinterpret_cast<const u16x8*>(A + (size_t)row * 128);
  for (int k8 = 0; k8 < 16; k8++) {
    u16x8 v = a8[k8];
    int k = k8 * 8;
    #pragma unroll
    for (int j = 0; j < 8; j++) {
      float f = fmaxf(bf2f(v[j]) * scs[k + j] + shs[k + j], 0.f);
      #pragma unroll
      for (int c = 0; c < 5; c++) acc[c] += f * Ws[(k + j) * 5 + c];
    }
  }
  #pragma unroll
  for (int j = 0; j < 5; j++) C[(size_t)row * 5 + j] = acc[j];
}

// ---------------- final aggregation + b3 + log_softmax ----------------
__global__ void agg3_lsm_kernel(const float* __restrict__ h, const int* __restrict__ offsets,
                                const int* __restrict__ csr, const float* __restrict__ inv_s,
                                const float* __restrict__ b3, float* __restrict__ out, int n) {
  int node = blockIdx.x * blockDim.x + threadIdx.x;
  if (node >= n) return;
  float di = inv_s[node];
  float acc[5];
  #pragma unroll
  for (int j = 0; j < 5; j++) acc[j] = h[(size_t)node * 5 + j] * di * di;
  int s0 = offsets[node], s1 = offsets[node + 1];
  for (int e = s0; e < s1; e++) {
    int s = csr[e];
    float wgt = inv_s[s] * di;
    #pragma unroll
    for (int j = 0; j < 5; j++) acc[j] += h[(size_t)s * 5 + j] * wgt;
  }
  #pragma unroll
  for (int j = 0; j < 5; j++) acc[j] += b3[j];
  float m = acc[0];
  #pragma unroll
  for (int j = 1; j < 5; j++) m = fmaxf(m, acc[j]);
  float sum = 0.f;
  #pragma unroll
  for (int j = 0; j < 5; j++) sum += expf(acc[j] - m);
  float lse = logf(sum);
  #pragma unroll
  for (int j = 0; j < 5; j++) out[(size_t)node * 5 + j] = acc[j] - m - lse;
}

// ---------------- launcher ----------------
extern "C" void kernel_launch(void* const* d_in, const int* in_sizes, int n_in,
                              void* d_out, int out_size, void* d_ws, size_t ws_size,
                              hipStream_t stream) {
  const float* x      = (const float*)d_in[0];
  const int*   ei     = (const int*)d_in[1];
  const float* W1     = (const float*)d_in[2];
  const float* b3     = (const float*)d_in[7];
  const float* W2     = (const float*)d_in[4];
  const float* W3     = (const float*)d_in[6];
  const float* gamma1 = (const float*)d_in[8];
  const float* beta1  = (const float*)d_in[9];
  const float* gamma2 = (const float*)d_in[10];
  const float* beta2  = (const float*)d_in[11];

  const int N = in_sizes[0] / 1536;
  const int E = in_sizes[1] / 2;
  const int* src = ei;
  const int* dst = ei + E;

  const int mblocks = (N + 127) / 128;      // 391
  const int nb = (N + 255) / 256;

  char* ws = (char*)d_ws;
  size_t szRA = alignup((size_t)N * 512 * sizeof(float));
  size_t szXB = alignup((size_t)(mblocks * 128) * 1536 * sizeof(unsigned short));
  char* RAb = ws;                            // region A (bf16 H1 / bf16 H2 / f32 H3)
  char* RBb = ws + szRA;                     // region B (G1/G2)
  char* sp = ws + szRA + szXB;
  int* counts   = (int*)sp;           sp += alignup((size_t)N * 4);
  int* cursor   = (int*)sp;           sp += alignup((size_t)N * 4);
  int* offsets  = (int*)sp;           sp += alignup((size_t)(N + 1) * 4);
  int* csr_src  = (int*)sp;           sp += alignup((size_t)E * 4);
  float* inv_s  = (float*)sp;         sp += alignup((size_t)N * 4);
  unsigned short* W1t = (unsigned short*)sp; sp += alignup((size_t)512 * 1536 * 2);
  unsigned short* W2t = (unsigned short*)sp; sp += alignup((size_t)128 * 512 * 2);
  float* accum  = (float*)sp;         sp += alignup(1024 * 4);
  float* sc1    = (float*)sp;         sp += alignup(512 * 4);
  float* sh1    = (float*)sp;         sp += alignup(512 * 4);
  float* sc2    = (float*)sp;         sp += alignup(128 * 4);
  float* sh2    = (float*)sp;         sp += alignup(128 * 4);
  int* bsum     = (int*)sp;           sp += alignup(256 * 4);

  unsigned short* H1  = (unsigned short*)RAb;  // N x 512 bf16
  unsigned short* G1  = (unsigned short*)RBb;  // N x 512 bf16 (post-agg)
  unsigned short* H2  = (unsigned short*)RAb;  // N x 128 bf16
  unsigned short* G2  = (unsigned short*)RBb;  // N x 128 bf16
  float*          H3  = (float*)RAb;           // N x 5 f32

  // ---- graph preprocessing ----
  hipMemsetAsync(counts, 0, (size_t)N * 4, stream);
  hipMemsetAsync(cursor, 0, (size_t)N * 4, stream);
  count_kernel<<<(E + 255) / 256, 256, 0, stream>>>(dst, counts, E);
  invsqrt_kernel<<<(N + 255) / 256, 256, 0, stream>>>(counts, inv_s, N);
  block_sum_kernel<<<nb, 256, 0, stream>>>(counts, bsum, N);
  scan_bsum_kernel<<<1, 256, 0, stream>>>(bsum, nb);
  scan_apply_kernel<<<nb, 256, 0, stream>>>(counts, bsum, offsets, N);
  fill_kernel<<<(E + 255) / 256, 256, 0, stream>>>(src, dst, offsets, cursor, csr_src, E);

  // ---- weights ----
  transpose_w_kernel<<<dim3(1536 / 32, 512 / 32), 256, 0, stream>>>(W1, W1t, 1536, 512);
  transpose_w_kernel<<<dim3(512 / 32, 128 / 32), 256, 0, stream>>>(W2, W2t, 512, 128);

  int aggblocks = (N + 3) / 4;
  int rpb = (N + 511) / 512;

  // ---- layer 1 (x f32 -> bf16 fused into pipelined A staging) ----
  gemm1_kernel<<<dim3(4, mblocks), 256, 0, stream>>>(x, W1t, H1, N);
  agg512_kernel<<<aggblocks, 256, 0, stream>>>(H1, offsets, csr_src, inv_s, G1, N);
  hipMemsetAsync(accum, 0, 1024 * 4, stream);
  bn_stats512_kernel<<<512, 256, 0, stream>>>(G1, accum, N, rpb);
  bn_finalize_kernel<<<2, 256, 0, stream>>>(accum, gamma1, beta1, sc1, sh1, 512, 1.0f / N);

  // ---- layer 2 (BN1+ReLU fused into A staging) ----
  gemm2_kernel<<<dim3(1, mblocks), 256, 0, stream>>>(G1, W2t, sc1, sh1, H2, N);
  agg128_kernel<<<aggblocks, 256, 0, stream>>>(H2, offsets, csr_src, inv_s, G2, N);
  hipMemsetAsync(accum, 0, 1024 * 4, stream);
  bn_stats128_kernel<<<512, 256, 0, stream>>>(G2, accum, N, rpb);
  bn_finalize_kernel<<<1, 256, 0, stream>>>(accum, gamma2, beta2, sc2, sh2, 128, 1.0f / N);

  // ---- layer 3 (BN2+ReLU fused) ----
  gemm3_kernel<<<(N + 255) / 256, 256, 0, stream>>>(G2, W3, sc2, sh2, H3, N);
  agg3_lsm_kernel<<<(N + 255) / 256, 256, 0, stream>>>(H3, offsets, csr_src, inv_s, b3,
                                                       (float*)d_out, N);
}